// Round 16
// baseline (275.674 us; speedup 1.0000x reference)
//
#include <hip/hip_runtime.h>
#include <hip/hip_bf16.h>

#define EPSV 1e-5f

// workspace layout: [wB2][xTp][stats]
#define WB2_ELEMS (2*8*36*128*32)          // [p][nt(8)][kt(36)][nl(128)][kk(32)] bf16
#define WB2_BYTES ((size_t)WB2_ELEMS*2)    // 4,718,592
#define XTP_ELEMS (8*68*68*128)            // padded channels-last x, bf16
#define XTP_BYTES ((size_t)XTP_ELEMS*2)    // 9,469,952
#define STATS_OFF (WB2_BYTES + XTP_BYTES)  // 1024 float2 partials

typedef __attribute__((ext_vector_type(8))) short short8;
typedef __attribute__((ext_vector_type(4))) float f32x4;

__device__ __forceinline__ void gload_lds16(const void* g, void* l) {
    __builtin_amdgcn_global_load_lds(
        (const __attribute__((address_space(1))) void*)g,
        (__attribute__((address_space(3))) void*)l, 16, 0, 0);
}

// ---------------------------------------------------------------------------
// x [8][128][64][64] f32  ->  xTp [8][68][68][128] bf16 (2-px zero halo)
__global__ __launch_bounds__(256) void k_xpad(const float* __restrict__ x,
                                              __hip_bfloat16* __restrict__ xTp) {
    int bh = blockIdx.x; int b = bh >> 6, h = bh & 63;
    __shared__ __hip_bfloat16 tile[64][130];
    int t = threadIdx.x;
#pragma unroll
    for (int i = 0; i < 32; ++i) {
        int e = (i << 8) + t; int w = e & 63; int ci = e >> 6;
        tile[w][ci] = __float2bfloat16(x[(((size_t)(b*128 + ci))*64 + h)*64 + w]);
    }
    __syncthreads();
    __hip_bfloat16* dst = xTp + ((size_t)((b*68 + h + 2)*68 + 2))*128;
#pragma unroll
    for (int i = 0; i < 32; ++i) {
        int e = (i << 8) + t; int ci = e & 127; int w = e >> 7;
        dst[w*128 + ci] = tile[w][ci];
    }
}

// ---------------------------------------------------------------------------
// w_mid [128][16][128][3][3] f32 -> wB2 [p][nt(8)][kt(36)][nl(128)][kk(32)]
__global__ void k_wrepack(const float* __restrict__ w_mid,
                          __hip_bfloat16* __restrict__ wB2) {
    int idx = blockIdx.x * 256 + threadIdx.x;
    if (idx >= WB2_ELEMS) return;
    int kk  = idx & 31;
    int nl  = (idx >> 5) & 127;
    int q   = idx >> 12;             // (p*8+nt)*36 + kt
    int kt  = q % 36;
    int pnt = q / 36;
    int nt  = pnt & 7, p = pnt >> 3;
    int c = ((nt*8 + (nl >> 4)) << 1) + p;
    int m = nl & 15;
    int k = kt*32 + kk;
    int tap = k >> 7, ci = k & 127;
    wB2[idx] = __float2bfloat16(w_mid[((size_t)((c*16 + m)*128 + ci))*9 + tap]);
}

// ---------------------------------------------------------------------------
// Implicit-GEMM conv with REGISTER fragment double-buffering:
// step u's MFMAs use fragments ds_read at step u-1; step u issues reads for
// u+1 — the lgkm wait lands a barrier+MFMA-cluster later (hidden). Staging:
// distance-3 into 4 rotating LDS buffer sets (64 KB -> 2 blocks/CU), counted
// vmcnt(4)/step (guarantees stage(u+1), leaves stage(u+2) in flight).
// BM=128, BN=128, BK=32, 4 waves (2x2), acc 4x4. All staging/swizzle/read
// formulas verbatim from the passing R10 kernel.
__global__ __launch_bounds__(256, 2) void k_conv(
    const __hip_bfloat16* __restrict__ xTp,
    const __hip_bfloat16* __restrict__ wB2,
    const float* __restrict__ w_pt,
    const float* __restrict__ b_pt,
    float* __restrict__ y) {
    __shared__ __hip_bfloat16 Alds[4*4096];   // 4 x 8 KB
    __shared__ __hip_bfloat16 Blds[4*4096];   // 4 x 8 KB

    // XCD x_ owns (p, mt-quarter): per-XCD working set = A ~2.4 MB + B 2.36 MB
    const int x_ = blockIdx.x & 7;
    const int p  = x_ & 1;
    const int mq = x_ >> 1;              // mt quarter 0..3
    const int i_ = blockIdx.x >> 3;      // 0..511
    const int nt = i_ & 7;
    const int mt = mq*64 + (i_ >> 3);    // 0..255
    const int dil = 1 + p;

    const int t = threadIdx.x;
    const int lane = t & 63;
    const int wave = t >> 6;
    const int wm = wave >> 1, wn = wave & 1;

    const int rsub = t >> 2;                              // staging row (0..63)
    const int ksub = (((t & 3) ^ ((t >> 3) & 3)) << 3);   // src-side swizzled slot

    // A source base pointers (tap center, k-chunk 0) per 64-row pass (R10)
    const __hip_bfloat16* abase0;
    const __hip_bfloat16* abase1;
    {
        int s0 = mt*128 + rsub;
        int s1 = s0 + 64;
        abase0 = xTp + ((size_t)(((s0>>12)*68 + ((s0>>6)&63) + 2)*68 + (s0&63) + 2))*128 + ksub;
        abase1 = xTp + ((size_t)(((s1>>12)*68 + ((s1>>6)&63) + 2)*68 + (s1&63) + 2))*128 + ksub;
    }
    // B source (R10): rows of the (p,nt,kt) 128x32 tile, swizzled slot
    const __hip_bfloat16* bntbase = wB2 + (size_t)p*(8*36*4096) + (size_t)nt*(36*4096)
                                  + rsub*32 + ksub;

    // staging issue for step u into buffer bufi (4 x gload_lds / thread)
#define ISSUE(u, bufi) do {                                                   \
    const int tap_ = (u) >> 2, kc_ = (u) & 3;                                 \
    const int kh_ = tap_/3 - 1, kw_ = tap_%3 - 1;                             \
    const int toff_ = dil*(128*(kh_*68 + kw_)) + kc_*32;                      \
    gload_lds16(abase0 + toff_, (char*)Alds + (bufi)*8192 + t*16);            \
    gload_lds16(abase1 + toff_, (char*)Alds + (bufi)*8192 + 4096 + t*16);     \
    gload_lds16(bntbase + (size_t)(u)*4096,        (char*)Blds + (bufi)*8192 + t*16);        \
    gload_lds16(bntbase + (size_t)(u)*4096 + 2048, (char*)Blds + (bufi)*8192 + 4096 + t*16); \
  } while (0)

    f32x4 acc[4][4];
#pragma unroll
    for (int i = 0; i < 4; ++i)
#pragma unroll
        for (int j = 0; j < 4; ++j) acc[i][j] = (f32x4){0.f, 0.f, 0.f, 0.f};

    const int lm = lane & 15;
    const int lg = lane >> 4;
    const int sslot = (lg ^ ((lm >> 1) & 3)) << 3;   // read-side swizzled slot
    int aoff[4], boff[4];
#pragma unroll
    for (int i = 0; i < 4; ++i) {
        aoff[i] = (wm*64 + i*16 + lm)*32 + sslot;
        boff[i] = (wn*64 + i*16 + lm)*32 + sslot;
    }

    // prologue: stage steps 0,1,2 (distance-3 pipe fill)
    ISSUE(0, 0);
    ISSUE(1, 1);
    ISSUE(2, 2);
    asm volatile("s_waitcnt vmcnt(8)" ::: "memory");   // step 0's 4 loads landed
    __builtin_amdgcn_s_barrier();
    __builtin_amdgcn_sched_barrier(0);

    short8 af[2][4], bf[2][4];
#pragma unroll
    for (int i = 0; i < 4; ++i) af[0][i] = *(const short8*)(Alds + aoff[i]);
#pragma unroll
    for (int j = 0; j < 4; ++j) bf[0][j] = *(const short8*)(Blds + boff[j]);

#pragma unroll
    for (int u = 0; u < 36; ++u) {
        // entry wait: stage(u+1) landed (reads below need it); stage(u+2) stays in flight
        if (u < 34) asm volatile("s_waitcnt vmcnt(4)" ::: "memory");
        else        asm volatile("s_waitcnt vmcnt(0)" ::: "memory");
        __builtin_amdgcn_s_barrier();
        __builtin_amdgcn_sched_barrier(0);
        if (u + 3 < 36) ISSUE(u + 3, (u + 3) & 3);
        if (u < 35) {
            const int nb = (u + 1) & 3;
#pragma unroll
            for (int i = 0; i < 4; ++i)
                af[(u+1)&1][i] = *(const short8*)(Alds + nb*4096 + aoff[i]);
#pragma unroll
            for (int j = 0; j < 4; ++j)
                bf[(u+1)&1][j] = *(const short8*)(Blds + nb*4096 + boff[j]);
        }
        __builtin_amdgcn_s_setprio(1);
#pragma unroll
        for (int i = 0; i < 4; ++i)
#pragma unroll
            for (int j = 0; j < 4; ++j)
                acc[i][j] = __builtin_amdgcn_mfma_f32_16x16x32_bf16(
                    af[u&1][i], bf[u&1][j], acc[i][j], 0, 0, 0);
        __builtin_amdgcn_s_setprio(0);
    }
#undef ISSUE

    // epilogue: leaky -> *w_pt -> reduce over m (16 lanes) -> +b_pt -> y (R10)
#pragma unroll
    for (int j = 0; j < 4; ++j) {
        int n_g = nt*128 + wn*64 + j*16 + lm;
        int c = ((n_g >> 4) << 1) + p;     // uniform across the 16-lane group
        float wp = w_pt[c*16 + lm];        // m == lm
        float bp = b_pt[c];
#pragma unroll
        for (int i = 0; i < 4; ++i) {
#pragma unroll
            for (int r = 0; r < 4; ++r) {
                float v = acc[i][j][r];
                v = v >= 0.f ? v : 0.1f*v;
                v *= wp;
                v += __shfl_xor(v, 1);
                v += __shfl_xor(v, 2);
                v += __shfl_xor(v, 4);
                v += __shfl_xor(v, 8);
                if (lm == 0) {
                    int s = mt*128 + wm*64 + i*16 + lg*4 + r;
                    int b = s >> 12, hw = s & 4095;
                    y[(size_t)(b*128 + c)*4096 + hw] = v + bp;
                }
            }
        }
    }
}

// ---------------------------------------------------------------------------
// per-(b,c)-plane partial sums (float4 loads, no atomics, deterministic)
__global__ __launch_bounds__(256) void k_ystat(const float* __restrict__ y,
                                               float2* __restrict__ partials) {
    int P = blockIdx.x;                 // plane = b*128 + c
    const float4* base = (const float4*)(y + (size_t)P*4096);
    int t = threadIdx.x;
    float s = 0.f, s2 = 0.f;
#pragma unroll
    for (int i = 0; i < 4; ++i) {
        float4 v = base[t + i*256];
        s  += v.x + v.y + v.z + v.w;
        s2 += v.x*v.x + v.y*v.y + v.z*v.z + v.w*v.w;
    }
#pragma unroll
    for (int o = 32; o; o >>= 1) { s += __shfl_down(s, o); s2 += __shfl_down(s2, o); }
    __shared__ float ss[4], ss2[4];
    if ((t & 63) == 0) { ss[t >> 6] = s; ss2[t >> 6] = s2; }
    __syncthreads();
    if (t == 0)
        partials[P] = make_float2(ss[0]+ss[1]+ss[2]+ss[3], ss2[0]+ss2[1]+ss2[2]+ss2[3]);
}

// BN finalize + apply + ReLU. Block covers 256 float4 = quarter of one plane.
__global__ __launch_bounds__(256) void k_bn_apply(float* __restrict__ y,
                                                  const float2* __restrict__ partials,
                                                  const float* __restrict__ gamma,
                                                  const float* __restrict__ beta) {
    int bid = blockIdx.x;
    int c = (bid >> 2) & 127;
    float s = 0.f, s2 = 0.f;
#pragma unroll
    for (int b = 0; b < 8; ++b) {
        float2 pr = partials[b*128 + c];
        s += pr.x; s2 += pr.y;
    }
    float mean = s * (1.f/32768.f);
    float var  = s2 * (1.f/32768.f) - mean*mean;
    float scale = gamma[c] * rsqrtf(var + EPSV);
    float shift = beta[c] - mean*scale;
    float4* y4 = (float4*)y;
    int idx = bid*256 + threadIdx.x;
    float4 v = y4[idx];
    v.x = fmaxf(v.x*scale + shift, 0.f);
    v.y = fmaxf(v.y*scale + shift, 0.f);
    v.z = fmaxf(v.z*scale + shift, 0.f);
    v.w = fmaxf(v.w*scale + shift, 0.f);
    y4[idx] = v;
}

// ---------------------------------------------------------------------------
extern "C" void kernel_launch(void* const* d_in, const int* in_sizes, int n_in,
                              void* d_out, int out_size, void* d_ws, size_t ws_size,
                              hipStream_t stream) {
    const float* x     = (const float*)d_in[0];
    const float* w_mid = (const float*)d_in[1];
    const float* w_pt  = (const float*)d_in[2];
    const float* b_pt  = (const float*)d_in[3];
    const float* gamma = (const float*)d_in[4];
    const float* beta  = (const float*)d_in[5];
    float* y = (float*)d_out;

    __hip_bfloat16* wB2 = (__hip_bfloat16*)d_ws;
    __hip_bfloat16* xTp = (__hip_bfloat16*)((char*)d_ws + WB2_BYTES);
    float2* partials    = (float2*)((char*)d_ws + STATS_OFF);

    hipMemsetAsync(xTp, 0, XTP_BYTES, stream);                  // zero halo
    k_xpad<<<512, 256, 0, stream>>>(x, xTp);
    k_wrepack<<<(WB2_ELEMS + 255) / 256, 256, 0, stream>>>(w_mid, wB2);
    k_conv<<<4096, 256, 0, stream>>>(xTp, wB2, w_pt, b_pt, y);
    k_ystat<<<1024, 256, 0, stream>>>(y, partials);
    k_bn_apply<<<4096, 256, 0, stream>>>(y, partials, gamma, beta);
}

// Round 17
// 270.753 us; speedup vs baseline: 1.0182x; 1.0182x over previous
//
#include <hip/hip_runtime.h>
#include <hip/hip_bf16.h>

#define EPSV 1e-5f

// workspace layout: [wB2][xTp][stats]
#define WB2_ELEMS (2*8*36*128*32)          // [p][nt(8)][kt(36)][nl(128)][kk(32)] bf16
#define WB2_BYTES ((size_t)WB2_ELEMS*2)    // 4,718,592
#define XTP_ELEMS (8*68*68*128)            // padded channels-last x, bf16
#define XTP_BYTES ((size_t)XTP_ELEMS*2)    // 9,469,952
#define STATS_OFF (WB2_BYTES + XTP_BYTES)  // 1024 float2 partials

typedef __attribute__((ext_vector_type(8))) short short8;
typedef __attribute__((ext_vector_type(4))) float f32x4;

// ---------------------------------------------------------------------------
// x [8][128][64][64] f32  ->  xTp [8][68][68][128] bf16 (2-px zero halo)
__global__ __launch_bounds__(256) void k_xpad(const float* __restrict__ x,
                                              __hip_bfloat16* __restrict__ xTp) {
    int bh = blockIdx.x; int b = bh >> 6, h = bh & 63;
    __shared__ __hip_bfloat16 tile[64][130];
    int t = threadIdx.x;
#pragma unroll
    for (int i = 0; i < 32; ++i) {
        int e = (i << 8) + t; int w = e & 63; int ci = e >> 6;
        tile[w][ci] = __float2bfloat16(x[(((size_t)(b*128 + ci))*64 + h)*64 + w]);
    }
    __syncthreads();
    __hip_bfloat16* dst = xTp + ((size_t)((b*68 + h + 2)*68 + 2))*128;
#pragma unroll
    for (int i = 0; i < 32; ++i) {
        int e = (i << 8) + t; int ci = e & 127; int w = e >> 7;
        dst[w*128 + ci] = tile[w][ci];
    }
}

// ---------------------------------------------------------------------------
// w_mid [128][16][128][3][3] f32 -> wB2 [p][nt(8)][kt(36)][nl(128)][kk(32)]
__global__ void k_wrepack(const float* __restrict__ w_mid,
                          __hip_bfloat16* __restrict__ wB2) {
    int idx = blockIdx.x * 256 + threadIdx.x;
    if (idx >= WB2_ELEMS) return;
    int kk  = idx & 31;
    int nl  = (idx >> 5) & 127;
    int q   = idx >> 12;             // (p*8+nt)*36 + kt
    int kt  = q % 36;
    int pnt = q / 36;
    int nt  = pnt & 7, p = pnt >> 3;
    int c = ((nt*8 + (nl >> 4)) << 1) + p;
    int m = nl & 15;
    int k = kt*32 + kk;
    int tap = k >> 7, ci = k & 127;
    wB2[idx] = __float2bfloat16(w_mid[((size_t)((c*16 + m)*128 + ci))*9 + tap]);
}

// ---------------------------------------------------------------------------
// Persistent-A implicit-GEMM conv, barrier-free K-loop.
// Block = (p, nt) x one 8x16 output tile; 4 waves (2M x 2N), wave 64x64,
// acc 4x4. A halo (12x20 px, 128 ci) staged ONCE into LDS as 4 quarter-ci
// planes [240 px][32 elem] — 64 B pixel stride + slot key lg^((px>>1)&3)
// == R10's measured-zero-conflict read shape. B: global->reg, breg[3][4],
// distance-2, fully unrolled (no cross-backedge state). NO barriers in the
// loop (A immutable, B private); 61.4 KB LDS + ~120 VGPR -> 2 blocks/CU so
// one block's staging overlaps the other's MFMA.
__global__ __launch_bounds__(256, 2) void k_conv(
    const __hip_bfloat16* __restrict__ xTp,
    const __hip_bfloat16* __restrict__ wB2,
    const float* __restrict__ w_pt,
    const float* __restrict__ b_pt,
    float* __restrict__ y) {
    __shared__ __hip_bfloat16 Atile[4*240*32];   // 61,440 B; plane kc: ci kc*32..+32

    const int combo = blockIdx.x & 7;      // XCD
    const int p   = combo & 1;
    const int ntp = combo >> 1;            // nt-pair 0..3
    const int i_  = blockIdx.x >> 3;       // 0..511
    const int nt  = ntp*2 + (i_ & 1);
    const int mt  = i_ >> 1;               // 0..255
    const int dil = 1 + p;
    const int b  = mt >> 5;                // image
    const int hb = (mt >> 2) & 7;          // row-block: output rows hb*8..+8
    const int wb = mt & 3;                 // col-block: output cols wb*16..+16
    const int H0 = hb*8, W0 = wb*16;       // halo origin (padded coords)

    const int t = threadIdx.x, lane = t & 63, wave = t >> 6;
    const int wm = wave >> 1, wn = wave & 1;
    const int lm = lane & 15, lg = lane >> 4;

    // ---- stage halo once: 4 planes x 240 px x 4 slots = 3840 units, 15 passes
    // thread handles logical (kc, px, ls); LDS write addr swizzled:
    // phys slot = ls ^ ((px>>1)&3)   (R6 mechanism, R10 read shape)
    {
        const size_t gbase = ((size_t)(b*68 + H0))*68 + W0;
#pragma unroll
        for (int pass = 0; pass < 15; ++pass) {
            int si  = pass*256 + t;          // 0..3839
            int kc  = si / 960;
            int rem = si - kc*960;
            int px  = rem >> 2;
            int ls  = rem & 3;
            int prow = px / 20, pcol = px - prow*20;
            short8 v = *(const short8*)(xTp + (gbase + prow*68 + pcol)*128
                                        + kc*32 + ls*8);
            int phys = ls ^ ((px >> 1) & 3);
            *(short8*)(Atile + (kc*960 + px*4 + phys)*8) = v;
        }
    }

    // B pointer (R7-proven direct-B formulas): frag j at step u = +u*4096+j*512
    const __hip_bfloat16* bptr = wB2 + (size_t)p*(8*36*4096) + (size_t)nt*(36*4096)
                               + (wn*64 + lm)*32 + lg*8;

    f32x4 acc[4][4];
#pragma unroll
    for (int i = 0; i < 4; ++i)
#pragma unroll
        for (int j = 0; j < 4; ++j) acc[i][j] = (f32x4){0.f, 0.f, 0.f, 0.f};

    // B prologue: steps 0,1 into breg[0],breg[1]
    short8 breg[3][4];
#pragma unroll
    for (int j = 0; j < 4; ++j) breg[0][j] = *(const short8*)(bptr + j*512);
#pragma unroll
    for (int j = 0; j < 4; ++j) breg[1][j] = *(const short8*)(bptr + 4096 + j*512);

    __syncthreads();   // staging visible; the ONLY block-wide barrier

#pragma unroll
    for (int u = 0; u < 36; ++u) {
        // B prefetch for step u+2 (distance-2, static %3 rotation, no backedge)
        if (u + 2 < 36) {
#pragma unroll
            for (int j = 0; j < 4; ++j)
                breg[(u+2)%3][j] = *(const short8*)(bptr + (size_t)(u+2)*4096 + j*512);
        }
        // A fragments from persistent quarter-plane LDS (compile-time tap)
        const int tap = u >> 2, kc = u & 3;
        const int kh = tap/3 - 1, kw = tap%3 - 1;
        short8 af[4];
        {
            int pc = 2 + dil*kw + lm;
            int pr = (wm*4 + 2 + dil*kh)*20 + pc;
#pragma unroll
            for (int i = 0; i < 4; ++i) {
                int px = pr + 20*i;
                af[i] = *(const short8*)(Atile + kc*7680 + px*32
                                         + ((lg ^ ((px >> 1) & 3)) << 3));
            }
        }
        __builtin_amdgcn_s_setprio(1);
#pragma unroll
        for (int i = 0; i < 4; ++i)
#pragma unroll
            for (int j = 0; j < 4; ++j)
                acc[i][j] = __builtin_amdgcn_mfma_f32_16x16x32_bf16(
                    af[i], breg[u%3][j], acc[i][j], 0, 0, 0);
        __builtin_amdgcn_s_setprio(0);
    }

    // epilogue: leaky -> *w_pt -> reduce over m (16 lanes) -> +b_pt -> y
#pragma unroll
    for (int j = 0; j < 4; ++j) {
        int n_g = nt*128 + wn*64 + j*16 + lm;
        int c = ((n_g >> 4) << 1) + p;     // uniform across the 16-lane group
        float wp = w_pt[c*16 + lm];        // m == lm
        float bp = b_pt[c];
#pragma unroll
        for (int i = 0; i < 4; ++i) {
            int h = H0 + wm*4 + i;
#pragma unroll
            for (int r = 0; r < 4; ++r) {
                float v = acc[i][j][r];
                v = v >= 0.f ? v : 0.1f*v;
                v *= wp;
                v += __shfl_xor(v, 1);
                v += __shfl_xor(v, 2);
                v += __shfl_xor(v, 4);
                v += __shfl_xor(v, 8);
                if (lm == 0) {
                    int w = W0 + lg*4 + r;
                    y[(size_t)(b*128 + c)*4096 + h*64 + w] = v + bp;
                }
            }
        }
    }
}

// ---------------------------------------------------------------------------
// per-(b,c)-plane partial sums (float4 loads, no atomics, deterministic)
__global__ __launch_bounds__(256) void k_ystat(const float* __restrict__ y,
                                               float2* __restrict__ partials) {
    int P = blockIdx.x;                 // plane = b*128 + c
    const float4* base = (const float4*)(y + (size_t)P*4096);
    int t = threadIdx.x;
    float s = 0.f, s2 = 0.f;
#pragma unroll
    for (int i = 0; i < 4; ++i) {
        float4 v = base[t + i*256];
        s  += v.x + v.y + v.z + v.w;
        s2 += v.x*v.x + v.y*v.y + v.z*v.z + v.w*v.w;
    }
#pragma unroll
    for (int o = 32; o; o >>= 1) { s += __shfl_down(s, o); s2 += __shfl_down(s2, o); }
    __shared__ float ss[4], ss2[4];
    if ((t & 63) == 0) { ss[t >> 6] = s; ss2[t >> 6] = s2; }
    __syncthreads();
    if (t == 0)
        partials[P] = make_float2(ss[0]+ss[1]+ss[2]+ss[3], ss2[0]+ss2[1]+ss2[2]+ss2[3]);
}

// BN finalize + apply + ReLU. Block covers 256 float4 = quarter of one plane.
__global__ __launch_bounds__(256) void k_bn_apply(float* __restrict__ y,
                                                  const float2* __restrict__ partials,
                                                  const float* __restrict__ gamma,
                                                  const float* __restrict__ beta) {
    int bid = blockIdx.x;
    int c = (bid >> 2) & 127;
    float s = 0.f, s2 = 0.f;
#pragma unroll
    for (int b = 0; b < 8; ++b) {
        float2 pr = partials[b*128 + c];
        s += pr.x; s2 += pr.y;
    }
    float mean = s * (1.f/32768.f);
    float var  = s2 * (1.f/32768.f) - mean*mean;
    float scale = gamma[c] * rsqrtf(var + EPSV);
    float shift = beta[c] - mean*scale;
    float4* y4 = (float4*)y;
    int idx = bid*256 + threadIdx.x;
    float4 v = y4[idx];
    v.x = fmaxf(v.x*scale + shift, 0.f);
    v.y = fmaxf(v.y*scale + shift, 0.f);
    v.z = fmaxf(v.z*scale + shift, 0.f);
    v.w = fmaxf(v.w*scale + shift, 0.f);
    y4[idx] = v;
}

// ---------------------------------------------------------------------------
extern "C" void kernel_launch(void* const* d_in, const int* in_sizes, int n_in,
                              void* d_out, int out_size, void* d_ws, size_t ws_size,
                              hipStream_t stream) {
    const float* x     = (const float*)d_in[0];
    const float* w_mid = (const float*)d_in[1];
    const float* w_pt  = (const float*)d_in[2];
    const float* b_pt  = (const float*)d_in[3];
    const float* gamma = (const float*)d_in[4];
    const float* beta  = (const float*)d_in[5];
    float* y = (float*)d_out;

    __hip_bfloat16* wB2 = (__hip_bfloat16*)d_ws;
    __hip_bfloat16* xTp = (__hip_bfloat16*)((char*)d_ws + WB2_BYTES);
    float2* partials    = (float2*)((char*)d_ws + STATS_OFF);

    hipMemsetAsync(xTp, 0, XTP_BYTES, stream);                  // zero halo
    k_xpad<<<512, 256, 0, stream>>>(x, xTp);
    k_wrepack<<<(WB2_ELEMS + 255) / 256, 256, 0, stream>>>(w_mid, wB2);
    k_conv<<<4096, 256, 0, stream>>>(xTp, wB2, w_pt, b_pt, y);
    k_ystat<<<1024, 256, 0, stream>>>(y, partials);
    k_bn_apply<<<4096, 256, 0, stream>>>(y, partials, gamma, beta);
}